// Round 15
// baseline (200.345 us; speedup 1.0000x reference)
//
#include <hip/hip_runtime.h>
#include <math.h>

#define N_NODES 50000
#define HID 128
#define N_EDGES 600000
#define GEMM_BLOCKS 782   // ceil(50000/64)
#define FILL_BLOCKS 586   // ceil(150000/256)

typedef __attribute__((ext_vector_type(8))) short s16x8;
typedef __attribute__((ext_vector_type(4))) float f32x4;
typedef __attribute__((ext_vector_type(2))) float f32x2;
typedef __attribute__((ext_vector_type(4))) uint u32x4;

// RNE float -> bf16 bits (finite inputs only)
__device__ __forceinline__ ushort f2b(float f) {
    uint x = __builtin_bit_cast(uint, f);
    uint r = (x + 0x7FFFu + ((x >> 16) & 1u)) >> 16;
    return (ushort)r;
}
__device__ __forceinline__ float blo(uint u) {           // low bf16 -> f32
    return __builtin_bit_cast(float, u << 16);
}
__device__ __forceinline__ float bhi(uint u) {           // high bf16 -> f32
    return __builtin_bit_cast(float, u & 0xffff0000u);
}
__device__ __forceinline__ float gelu_exact(float y) {
    return 0.5f * y * (1.0f + erff(y * 0.70710678118654752f));
}

// ------------------- prep: wfrag swizzle + cnt zero + hs zero-row ----------
// wfrag word ((ct*4+ks)*64 + lane)*4 + w holds bf16 pair (W[k0][n], W[k0+1][n]),
// k0 = ks*32 + (lane>>4)*8 + 2w, n = ct*16 + (lane&15). Two matrices.
__global__ __launch_bounds__(256) void prep_kernel(
        const float* __restrict__ W1, const float* __restrict__ W2,
        uint* __restrict__ wfrag, u32x4* __restrict__ cnt4, int n4,
        u32x4* __restrict__ hs4) {
    int id = blockIdx.x * 256 + threadIdx.x;
    if (id < 16384) {
        const float* W = (id < 8192) ? W1 : W2;
        int q = id & 8191;
        int l16 = q & 15;
        int w   = (q >> 4) & 3;
        int kg  = (q >> 6) & 3;
        int f   = q >> 8;                         // ct*4+ks, 0..31
        int ct = f >> 2, ks = f & 3;
        int n  = ct * 16 + l16;
        int k0 = ks * 32 + kg * 8 + 2 * w;
        uint lo = f2b(W[(size_t)k0 * HID + n]);
        uint hi = f2b(W[(size_t)(k0 + 1) * HID + n]);
        size_t widx = ((size_t)(id >> 13) * 8192) +
                      ((size_t)f * 64 + kg * 16 + l16) * 4 + w;
        wfrag[widx] = lo | (hi << 16);
    } else if (id < 16384 + n4) {
        cnt4[id - 16384] = (u32x4)(0u);
    } else if (id < 16384 + n4 + 16) {
        hs4[(size_t)N_NODES * 16 + (id - 16384 - n4)] = (u32x4)(0u);  // zero row
    }
}

// ---------------------------------------------------------------- degree ----
__global__ void count_deg_kernel(const int4* __restrict__ dst4, int* cnt, int e4) {
    int i = blockIdx.x * blockDim.x + threadIdx.x;
    if (i < e4) {
        int4 d = dst4[i];
        atomicAdd(&cnt[d.x], 1); atomicAdd(&cnt[d.y], 1);
        atomicAdd(&cnt[d.z], 1); atomicAdd(&cnt[d.w], 1);
    }
}

// fused: dinv[i] = rsqrt(cnt[i]+1)  AND  bsum[blk] = sum(cnt)
__global__ __launch_bounds__(256) void reduce_dinv_kernel(
        const int* __restrict__ cnt, float* __restrict__ dinv,
        int* __restrict__ bsum, int n) {
    int i = blockIdx.x * 256 + threadIdx.x;
    int v = (i < n) ? cnt[i] : 0;
    if (i < n) dinv[i] = rsqrtf((float)(v + 1));   // +1 self-loop
#pragma unroll
    for (int off = 32; off >= 1; off >>= 1) v += __shfl_xor(v, off);
    __shared__ int ws[4];
    if ((threadIdx.x & 63) == 0) ws[threadIdx.x >> 6] = v;
    __syncthreads();
    if (threadIdx.x == 0) bsum[blockIdx.x] = ws[0] + ws[1] + ws[2] + ws[3];
}

// scan: each block redundantly prefix-sums bsum[0..blockIdx) (cheap; removes
// the 1-block scan_bsum bubble), then local exclusive scan of cnt -> offs.
__global__ __launch_bounds__(256) void scan_csr_kernel(
        const int* __restrict__ cnt, const int* __restrict__ bsum,
        int* __restrict__ offs, int n, int nb) {
    int t = threadIdx.x;
    int pv = (t < nb && t < (int)blockIdx.x) ? bsum[t] : 0;
#pragma unroll
    for (int off = 32; off >= 1; off >>= 1) pv += __shfl_xor(pv, off);
    __shared__ int wsum[4];
    if ((t & 63) == 0) wsum[t >> 6] = pv;
    __syncthreads();
    int base = wsum[0] + wsum[1] + wsum[2] + wsum[3];

    int i = blockIdx.x * 256 + t;
    int v = (i < n) ? cnt[i] : 0;
    int x = v;
#pragma unroll
    for (int off = 1; off < 64; off <<= 1) {
        int y = __shfl_up(x, off);
        if ((t & 63) >= off) x += y;
    }
    __shared__ int wtot[4];
    if ((t & 63) == 63) wtot[t >> 6] = x;
    __syncthreads();
    int add = base;
    for (int w = 0; w < (t >> 6); ++w) add += wtot[w];
    if (i < n) offs[i] = x - v + add;    // exclusive scan = segment start
}

// ------------------------------------------------------------ GEMM body -----
// H = dinv[r] * (A[r][:] @ W), W pre-swizzled in fragment order (LDS 32 KB,
// lane-linear ds_read -> 0 bank conflicts). Packed node-major store:
// word w (0..63) of row = bf16 pair of cols ((w>>4)*32 + (w&15), +16).
template<bool AB16>
__device__ __forceinline__ void gemm_body(
        int bid, const void* __restrict__ Ap, const uint* __restrict__ wfrag,
        const float* __restrict__ dinv, uint* __restrict__ H, int M) {
    __shared__ u32x4 Wl[2048];                    // 32 KB, fragment order
    const u32x4* wf4 = (const u32x4*)wfrag;
#pragma unroll
    for (int i = 0; i < 8; ++i)
        Wl[threadIdx.x + i * 256] = wf4[threadIdx.x + i * 256];
    __syncthreads();

    const int l  = threadIdx.x & 63;
    const int wv = threadIdx.x >> 6;
    const int r0 = bid * 64 + wv * 16;
    if (r0 >= M) return;              // M % 16 == 0 -> whole waves only
    const int arow = r0 + (l & 15);
    const int kg = l >> 4;            // 0..3
    const int l16 = l & 15;

    s16x8 afr[4];
    if (AB16) {
        const ushort* A = (const ushort*)Ap + (size_t)arow * HID;
#pragma unroll
        for (int ks = 0; ks < 4; ++ks)
            afr[ks] = __builtin_nontemporal_load(
                          (const s16x8*)(A + ks * 32 + kg * 8));
    } else {
        const float* A = (const float*)Ap + (size_t)arow * HID;
#pragma unroll
        for (int ks = 0; ks < 4; ++ks) {
            int k0 = ks * 32 + kg * 8;
            f32x4 a0 = __builtin_nontemporal_load((const f32x4*)(A + k0));
            f32x4 a1 = __builtin_nontemporal_load((const f32x4*)(A + k0 + 4));
            s16x8 v;
            v[0] = (short)f2b(a0.x); v[1] = (short)f2b(a0.y);
            v[2] = (short)f2b(a0.z); v[3] = (short)f2b(a0.w);
            v[4] = (short)f2b(a1.x); v[5] = (short)f2b(a1.y);
            v[6] = (short)f2b(a1.z); v[7] = (short)f2b(a1.w);
            afr[ks] = v;
        }
    }

    float drv[4];
#pragma unroll
    for (int q = 0; q < 4; ++q) drv[q] = dinv[r0 + kg * 4 + q];

    f32x4 acc[8];
#pragma unroll
    for (int ct = 0; ct < 8; ++ct) acc[ct] = (f32x4)(0.f);

    const ushort* Wls = (const ushort*)Wl;
#pragma unroll
    for (int ct = 0; ct < 8; ++ct) {
#pragma unroll
        for (int ks = 0; ks < 4; ++ks) {
            s16x8 bfr = *(const s16x8*)(Wls + ((ct * 4 + ks) * 64 + l) * 8);
            acc[ct] = __builtin_amdgcn_mfma_f32_16x16x32_bf16(
                          afr[ks], bfr, acc[ct], 0, 0, 0);
        }
    }

    // packed node-major store: word s*16+l16 of row = (acc[2s], acc[2s+1])
#pragma unroll
    for (int s = 0; s < 4; ++s) {
#pragma unroll
        for (int q = 0; q < 4; ++q) {
            int row = r0 + kg * 4 + q;
            uint wlo = f2b(acc[2 * s][q] * drv[q]);
            uint whi = f2b(acc[2 * s + 1][q] * drv[q]);
            H[(size_t)row * 64 + s * 16 + l16] = wlo | (whi << 16);
        }
    }
}

// gemm1 (fp32 A) co-launched with fill_csr: independent work, grid-split.
__global__ __launch_bounds__(256) void gemm1_fill_kernel(
        const float* __restrict__ x, const uint* __restrict__ wfrag,
        const float* __restrict__ dinv, uint* __restrict__ H,
        const int4* __restrict__ src4, const int4* __restrict__ dst4,
        int* __restrict__ offs, int* __restrict__ srcPerm, int e4) {
    if ((int)blockIdx.x < GEMM_BLOCKS) {
        gemm_body<false>(blockIdx.x, x, wfrag, dinv, H, N_NODES);
    } else {
        int i = ((int)blockIdx.x - GEMM_BLOCKS) * 256 + threadIdx.x;
        if (i < e4) {
            int4 s = src4[i];
            int4 d = dst4[i];
            srcPerm[atomicAdd(&offs[d.x], 1)] = s.x;
            srcPerm[atomicAdd(&offs[d.y], 1)] = s.y;
            srcPerm[atomicAdd(&offs[d.z], 1)] = s.z;
            srcPerm[atomicAdd(&offs[d.w], 1)] = s.w;
        }
    }
}

__global__ __launch_bounds__(256) void gemm2_kernel(
        const ushort* __restrict__ z1, const uint* __restrict__ wfrag,
        const float* __restrict__ dinv, uint* __restrict__ H) {
    gemm_body<true>(blockIdx.x, z1, wfrag, dinv, H, N_NODES);
}

// ----------------------------------- aggregate + LayerNorm + GELU (fused) ---
// 16-lane group per node (16 nodes/block). Lane l16 owns words 4*l16..4*l16+3
// of the packed row = cols colL..colL+3 and colL+16..+19, colL =
// (l16>>2)*32 + (l16&3)*4. Per 16-edge chunk: lane-parallel NT index fetch
// (double-buffered), 16 independent 16 B row-gathers (u32x4). Tail lanes use
// the zero row at index N (no masking). LN stats via 16-lane shfl (full row).
template<bool OUT_F32>
__global__ __launch_bounds__(256) void agg_ln_kernel(
        const u32x4* __restrict__ hs4, const float* __restrict__ dinv,
        const int* __restrict__ offsEnd, const int* __restrict__ srcPerm,
        const float* __restrict__ b, const float* __restrict__ g,
        const float* __restrict__ be,
        uint* __restrict__ z1, float* __restrict__ outf) {
    const int tid = threadIdx.x;
    const int l16 = tid & 15;
    const int grp = tid >> 4;              // node within block, 0..15
    const int gw16 = tid & 48;             // group base lane within wave
    const int d = blockIdx.x * 16 + grp;   // 3125 * 16 == N exactly
    const int colL = ((l16 >> 2) << 5) + ((l16 & 3) << 2);

    u32x4 u0 = hs4[(uint)(d * 16 + l16)];  // self-loop (pre-scaled)
    float aL[4], aH[4];
#pragma unroll
    for (int k = 0; k < 4; ++k) { aL[k] = blo(u0[k]); aH[k] = bhi(u0[k]); }

    const int beg = (d == 0) ? 0 : offsEnd[d - 1];
    const int end = offsEnd[d];

    int idx = (beg + l16 < end)
            ? __builtin_nontemporal_load(srcPerm + beg + l16) : N_NODES;

    for (int base = beg; base < end; base += 16) {
        int nbase = base + 16;
        int nidx = (nbase + l16 < end)
                 ? __builtin_nontemporal_load(srcPerm + nbase + l16) : N_NODES;

        u32x4 uu[16];
#pragma unroll
        for (int j = 0; j < 16; ++j) {
            int s = __shfl(idx, gw16 + j);       // N_NODES (zero row) if OOB
            uu[j] = hs4[(uint)(s * 16 + l16)];
        }
#pragma unroll
        for (int j = 0; j < 16; ++j) {
#pragma unroll
            for (int k = 0; k < 4; ++k) {
                aL[k] += blo(uu[j][k]);
                aH[k] += bhi(uu[j][k]);
            }
        }
        idx = nidx;
    }

    const float dd = dinv[d];
    float vL[4], vH[4];
    float s = 0.f, s2 = 0.f;
#pragma unroll
    for (int k = 0; k < 4; ++k) {
        int c = colL + k;
        vL[k] = aL[k] * dd + b[c];
        vH[k] = aH[k] * dd + b[c + 16];
        s  += vL[k] + vH[k];
        s2 += vL[k] * vL[k] + vH[k] * vH[k];
    }
#pragma unroll
    for (int off = 1; off < 16; off <<= 1) {
        s  += __shfl_xor(s,  off);
        s2 += __shfl_xor(s2, off);
    }
    float mu   = s  * (1.0f / 128.0f);
    float var  = s2 * (1.0f / 128.0f) - mu * mu;
    float rstd = rsqrtf(var + 1e-5f);

    if (OUT_F32) {
        __shared__ float ft[16][HID];
#pragma unroll
        for (int k = 0; k < 4; ++k) {
            int c = colL + k;
            ft[grp][c]      = gelu_exact((vL[k] - mu) * rstd * g[c]      + be[c]);
            ft[grp][c + 16] = gelu_exact((vH[k] - mu) * rstd * g[c + 16] + be[c + 16]);
        }
        __syncthreads();
#pragma unroll
        for (int i = 0; i < 4; ++i) {
            int q = tid + i * 256;             // float2 pair index, 0..1023
            int node = q >> 6, w = q & 63;
            f32x2 val = *(const f32x2*)&ft[node][2 * w];
            __builtin_nontemporal_store(
                val, (f32x2*)&outf[((size_t)blockIdx.x * 16 + node) * HID + 2 * w]);
        }
    } else {
        __shared__ ushort zt[16][HID];
#pragma unroll
        for (int k = 0; k < 4; ++k) {
            int c = colL + k;
            zt[grp][c]      = f2b(gelu_exact((vL[k] - mu) * rstd * g[c]      + be[c]));
            zt[grp][c + 16] = f2b(gelu_exact((vH[k] - mu) * rstd * g[c + 16] + be[c + 16]));
        }
        __syncthreads();
#pragma unroll
        for (int i = 0; i < 4; ++i) {
            int q = tid + i * 256;             // u32 word index, 0..1023
            int node = q >> 6, w = q & 63;
            uint val = *(const uint*)&zt[node][2 * w];
            z1[((size_t)blockIdx.x * 16 + node) * 64 + w] = val;
        }
    }
}

// ---------------------------------------------------------------- launch ----
extern "C" void kernel_launch(void* const* d_in, const int* in_sizes, int n_in,
                              void* d_out, int out_size, void* d_ws, size_t ws_size,
                              hipStream_t stream) {
    const float* x   = (const float*)d_in[0];
    const int*   ei  = (const int*)d_in[1];   // [2, E] int32
    const float* W1  = (const float*)d_in[2];
    const float* b1  = (const float*)d_in[3];
    const float* W2  = (const float*)d_in[4];
    const float* b2  = (const float*)d_in[5];
    const float* g1  = (const float*)d_in[6];
    const float* be1 = (const float*)d_in[7];
    const float* g2  = (const float*)d_in[8];
    const float* be2 = (const float*)d_in[9];
    float* out = (float*)d_out;

    const int* src = ei;
    const int* dst = ei + N_EDGES;

    // ws: hs packed [N+1][64] u32 | z1 bf16 [N][128] | srcPerm [E]
    //     | dinv [N] | offs [N] | cnt [N+pad] | bsum [256] | wfrag [2][8192]
    uint*   hs      = (uint*)d_ws;
    ushort* z1      = (ushort*)(hs + (size_t)(N_NODES + 1) * 64);
    int*    srcPerm = (int*)(z1 + (size_t)N_NODES * HID);
    float*  dinv    = (float*)(srcPerm + N_EDGES);
    int*    offs    = (int*)(dinv + N_NODES);
    int*    cnt     = offs + N_NODES;
    int*    bsum    = cnt + 50016;               // cnt padded to /16
    uint*   wfrag   = (uint*)(bsum + 256);

    const int B = 256;
    const int nodeB = (N_NODES + B - 1) / B;            // 196
    const int e4    = N_EDGES / 4;                      // 150000 (exact)
    const int edge4B = (e4 + B - 1) / B;                // 586
    const int agg_blocks = N_NODES / 16;                // 3125 (exact)
    const int zero4 = 50016 / 4;                        // 12504
    const int prepB = (16384 + zero4 + 16 + B - 1) / B; // 113

    // prep (wfrag + cnt zero + hs zero-row), degree, dinv, scan
    prep_kernel<<<prepB, B, 0, stream>>>(W1, W2, wfrag, (u32x4*)cnt, zero4,
                                         (u32x4*)hs);
    count_deg_kernel<<<edge4B, B, 0, stream>>>((const int4*)dst, cnt, e4);
    reduce_dinv_kernel<<<nodeB, B, 0, stream>>>(cnt, dinv, bsum, N_NODES);
    scan_csr_kernel<<<nodeB, B, 0, stream>>>(cnt, bsum, offs, N_NODES, nodeB);

    // gemm1 (x fp32 -> hs packed) co-launched with CSR fill
    gemm1_fill_kernel<<<GEMM_BLOCKS + FILL_BLOCKS, B, 0, stream>>>(
        x, wfrag, dinv, hs, (const int4*)src, (const int4*)dst,
        offs, srcPerm, e4);
    // post-fill: offs[d] == end of segment d

    // layer 1 aggregate + LN + GELU -> z1 bf16
    agg_ln_kernel<false><<<agg_blocks, B, 0, stream>>>(
        (const u32x4*)hs, dinv, offs, srcPerm, b1, g1, be1,
        (uint*)z1, nullptr);

    // layer 2: gemm (z1 bf16 -> hs packed), aggregate + LN + GELU -> out fp32
    gemm2_kernel<<<GEMM_BLOCKS, B, 0, stream>>>(z1, wfrag + 8192, dinv, hs);
    agg_ln_kernel<true><<<agg_blocks, B, 0, stream>>>(
        (const u32x4*)hs, dinv, offs, srcPerm, b2, g2, be2,
        nullptr, out);
}

// Round 16
// 180.341 us; speedup vs baseline: 1.1109x; 1.1109x over previous
//
#include <hip/hip_runtime.h>
#include <math.h>

#define N_NODES 50000
#define HID 128
#define N_EDGES 600000

typedef __attribute__((ext_vector_type(8))) short s16x8;
typedef __attribute__((ext_vector_type(4))) float f32x4;
typedef __attribute__((ext_vector_type(4))) uint u32x4;

// RNE float -> bf16 bits (finite inputs only)
__device__ __forceinline__ ushort f2b(float f) {
    uint x = __builtin_bit_cast(uint, f);
    uint r = (x + 0x7FFFu + ((x >> 16) & 1u)) >> 16;
    return (ushort)r;
}
__device__ __forceinline__ float blo(uint u) {           // low bf16 -> f32
    return __builtin_bit_cast(float, u << 16);
}
__device__ __forceinline__ float bhi(uint u) {           // high bf16 -> f32
    return __builtin_bit_cast(float, u & 0xffff0000u);
}
__device__ __forceinline__ float gelu_exact(float y) {
    return 0.5f * y * (1.0f + erff(y * 0.70710678118654752f));
}

// ------------------- prep: wfrag swizzle + cnt zero + hs zero-row ----------
__global__ __launch_bounds__(256) void prep_kernel(
        const float* __restrict__ W1, const float* __restrict__ W2,
        uint* __restrict__ wfrag, u32x4* __restrict__ cnt4, int n4,
        u32x4* __restrict__ hs4) {
    int id = blockIdx.x * 256 + threadIdx.x;
    if (id < 16384) {
        const float* W = (id < 8192) ? W1 : W2;
        int q = id & 8191;
        int l16 = q & 15;
        int w   = (q >> 4) & 3;
        int kg  = (q >> 6) & 3;
        int f   = q >> 8;                         // ct*4+ks, 0..31
        int ct = f >> 2, ks = f & 3;
        int n  = ct * 16 + l16;
        int k0 = ks * 32 + kg * 8 + 2 * w;
        uint lo = f2b(W[(size_t)k0 * HID + n]);
        uint hi = f2b(W[(size_t)(k0 + 1) * HID + n]);
        size_t widx = ((size_t)(id >> 13) * 8192) +
                      ((size_t)f * 64 + kg * 16 + l16) * 4 + w;
        wfrag[widx] = lo | (hi << 16);
    } else if (id < 16384 + n4) {
        cnt4[id - 16384] = (u32x4)(0u);
    } else if (id < 16384 + n4 + 16) {
        hs4[(size_t)N_NODES * 16 + (id - 16384 - n4)] = (u32x4)(0u);  // zero row
    }
}

// ---------------------------------------------------------------- degree ----
__global__ void count_deg_kernel(const int4* __restrict__ dst4, int* cnt, int e4) {
    int i = blockIdx.x * blockDim.x + threadIdx.x;
    if (i < e4) {
        int4 d = dst4[i];
        atomicAdd(&cnt[d.x], 1); atomicAdd(&cnt[d.y], 1);
        atomicAdd(&cnt[d.z], 1); atomicAdd(&cnt[d.w], 1);
    }
}

// fused: dinv[i] = rsqrt(cnt[i]+1)  AND  bsum[blk] = sum(cnt)
__global__ __launch_bounds__(256) void reduce_dinv_kernel(
        const int* __restrict__ cnt, float* __restrict__ dinv,
        int* __restrict__ bsum, int n) {
    int i = blockIdx.x * 256 + threadIdx.x;
    int v = (i < n) ? cnt[i] : 0;
    if (i < n) dinv[i] = rsqrtf((float)(v + 1));   // +1 self-loop
#pragma unroll
    for (int off = 32; off >= 1; off >>= 1) v += __shfl_xor(v, off);
    __shared__ int ws[4];
    if ((threadIdx.x & 63) == 0) ws[threadIdx.x >> 6] = v;
    __syncthreads();
    if (threadIdx.x == 0) bsum[blockIdx.x] = ws[0] + ws[1] + ws[2] + ws[3];
}

// scan: each block redundantly prefix-sums bsum[0..blockIdx), then local scan.
__global__ __launch_bounds__(256) void scan_csr_kernel(
        const int* __restrict__ cnt, const int* __restrict__ bsum,
        int* __restrict__ offs, int n, int nb) {
    int t = threadIdx.x;
    int pv = (t < nb && t < (int)blockIdx.x) ? bsum[t] : 0;
#pragma unroll
    for (int off = 32; off >= 1; off >>= 1) pv += __shfl_xor(pv, off);
    __shared__ int wsum[4];
    if ((t & 63) == 0) wsum[t >> 6] = pv;
    __syncthreads();
    int base = wsum[0] + wsum[1] + wsum[2] + wsum[3];

    int i = blockIdx.x * 256 + t;
    int v = (i < n) ? cnt[i] : 0;
    int x = v;
#pragma unroll
    for (int off = 1; off < 64; off <<= 1) {
        int y = __shfl_up(x, off);
        if ((t & 63) >= off) x += y;
    }
    __shared__ int wtot[4];
    if ((t & 63) == 63) wtot[t >> 6] = x;
    __syncthreads();
    int add = base;
    for (int w = 0; w < (t >> 6); ++w) add += wtot[w];
    if (i < n) offs[i] = x - v + add;    // exclusive scan = segment start
}

__global__ void fill_csr_kernel(const int4* __restrict__ src4,
                                const int4* __restrict__ dst4,
                                int* __restrict__ offs,
                                int* __restrict__ srcPerm, int e4) {
    int i = blockIdx.x * blockDim.x + threadIdx.x;
    if (i < e4) {
        int4 s = src4[i];
        int4 d = dst4[i];
        srcPerm[atomicAdd(&offs[d.x], 1)] = s.x;
        srcPerm[atomicAdd(&offs[d.y], 1)] = s.y;
        srcPerm[atomicAdd(&offs[d.z], 1)] = s.z;
        srcPerm[atomicAdd(&offs[d.w], 1)] = s.w;
    }
}

// ------------------------------------------------------------ GEMM body -----
// H = dinv[r] * (A[r][:] @ W), W pre-swizzled in fragment order (LDS 32 KB,
// lane-linear ds_read -> 0 bank conflicts). Packed node-major store:
// word w = s*16+j of row = bf16 pair of cols (32s + j, 32s + 16 + j).
template<bool AB16>
__device__ __forceinline__ void gemm_body(
        int bid, const void* __restrict__ Ap, const uint* __restrict__ wfrag,
        const float* __restrict__ dinv, uint* __restrict__ H, int M) {
    __shared__ u32x4 Wl[2048];                    // 32 KB, fragment order
    const u32x4* wf4 = (const u32x4*)wfrag;
#pragma unroll
    for (int i = 0; i < 8; ++i)
        Wl[threadIdx.x + i * 256] = wf4[threadIdx.x + i * 256];
    __syncthreads();

    const int l  = threadIdx.x & 63;
    const int wv = threadIdx.x >> 6;
    const int r0 = bid * 64 + wv * 16;
    if (r0 >= M) return;              // M % 16 == 0 -> whole waves only
    const int arow = r0 + (l & 15);
    const int kg = l >> 4;            // 0..3
    const int l16 = l & 15;

    s16x8 afr[4];
    if (AB16) {
        const ushort* A = (const ushort*)Ap + (size_t)arow * HID;
#pragma unroll
        for (int ks = 0; ks < 4; ++ks)
            afr[ks] = __builtin_nontemporal_load(
                          (const s16x8*)(A + ks * 32 + kg * 8));
    } else {
        const float* A = (const float*)Ap + (size_t)arow * HID;
#pragma unroll
        for (int ks = 0; ks < 4; ++ks) {
            int k0 = ks * 32 + kg * 8;
            f32x4 a0 = __builtin_nontemporal_load((const f32x4*)(A + k0));
            f32x4 a1 = __builtin_nontemporal_load((const f32x4*)(A + k0 + 4));
            s16x8 v;
            v[0] = (short)f2b(a0.x); v[1] = (short)f2b(a0.y);
            v[2] = (short)f2b(a0.z); v[3] = (short)f2b(a0.w);
            v[4] = (short)f2b(a1.x); v[5] = (short)f2b(a1.y);
            v[6] = (short)f2b(a1.z); v[7] = (short)f2b(a1.w);
            afr[ks] = v;
        }
    }

    float drv[4];
#pragma unroll
    for (int q = 0; q < 4; ++q) drv[q] = dinv[r0 + kg * 4 + q];

    f32x4 acc[8];
#pragma unroll
    for (int ct = 0; ct < 8; ++ct) acc[ct] = (f32x4)(0.f);

    const ushort* Wls = (const ushort*)Wl;
#pragma unroll
    for (int ct = 0; ct < 8; ++ct) {
#pragma unroll
        for (int ks = 0; ks < 4; ++ks) {
            s16x8 bfr = *(const s16x8*)(Wls + ((ct * 4 + ks) * 64 + l) * 8);
            acc[ct] = __builtin_amdgcn_mfma_f32_16x16x32_bf16(
                          afr[ks], bfr, acc[ct], 0, 0, 0);
        }
    }

#pragma unroll
    for (int s = 0; s < 4; ++s) {
#pragma unroll
        for (int q = 0; q < 4; ++q) {
            int row = r0 + kg * 4 + q;
            uint wlo = f2b(acc[2 * s][q] * drv[q]);
            uint whi = f2b(acc[2 * s + 1][q] * drv[q]);
            H[(size_t)row * 64 + s * 16 + l16] = wlo | (whi << 16);
        }
    }
}

__global__ __launch_bounds__(256) void gemm1_kernel(
        const float* __restrict__ x, const uint* __restrict__ wfrag,
        const float* __restrict__ dinv, uint* __restrict__ H) {
    gemm_body<false>(blockIdx.x, x, wfrag, dinv, H, N_NODES);
}

__global__ __launch_bounds__(256) void gemm2_kernel(
        const ushort* __restrict__ z1, const uint* __restrict__ wfrag,
        const float* __restrict__ dinv, uint* __restrict__ H) {
    gemm_body<true>(blockIdx.x, z1, wfrag, dinv, H, N_NODES);
}

// ----------------------------------- aggregate + LayerNorm + GELU (fused) ---
// ONE NODE PER WAVE (4 nodes/block, no cross-wave sync). 64-edge index
// window preloaded lane-parallel (NT). Subgroup sg = lane>>4 gathers edge
// 4i+sg: one u32x4 (16 B) per lane -> 4 edges per load instruction, unroll
// 4 -> 16 edges in flight. Tail edges read the zero row at index N (no
// masking). Subgroup partials folded by shfl_xor(16/32); LN stats via
// 4-bit xor reduce; GELU + store split across subgroups (2 values/lane).
template<bool OUT_F32>
__global__ __launch_bounds__(256) void agg_ln_kernel(
        const u32x4* __restrict__ hs4, const float* __restrict__ dinv,
        const int* __restrict__ offsEnd, const int* __restrict__ srcPerm,
        const float* __restrict__ b, const float* __restrict__ g,
        const float* __restrict__ be,
        ushort* __restrict__ z1, float* __restrict__ outf) {
    const int tid = threadIdx.x;
    const int l   = tid & 63;
    const int wv  = tid >> 6;
    const int l16 = l & 15;
    const int sg  = l >> 4;                 // subgroup 0..3
    const int d   = blockIdx.x * 4 + wv;    // 12500 * 4 == N exactly
    const int colL = ((l16 >> 2) << 5) + ((l16 & 3) << 2);

    u32x4 u0 = hs4[(uint)(d * 16 + l16)];   // self-loop row (added post-reduce)

    float aL[4] = {0.f, 0.f, 0.f, 0.f};
    float aH[4] = {0.f, 0.f, 0.f, 0.f};

    const int beg = (d == 0) ? 0 : offsEnd[d - 1];
    const int end = offsEnd[d];

    for (int wbase = beg; wbase < end; wbase += 64) {
        // 64-edge index window, lane-parallel coalesced NT load
        int idx = (wbase + l < end)
                ? __builtin_nontemporal_load(srcPerm + wbase + l) : N_NODES;
        int nIter = (end - wbase + 3) >> 2;          // 4 edges per iter
        if (nIter > 16) nIter = 16;
        for (int i = 0; i < nIter; i += 4) {
            u32x4 uu[4];
#pragma unroll
            for (int c = 0; c < 4; ++c) {
                int s = __shfl(idx, 4 * (i + c) + sg);   // zero row if OOB
                uu[c] = hs4[(uint)(s * 16 + l16)];
            }
#pragma unroll
            for (int c = 0; c < 4; ++c) {
#pragma unroll
                for (int k = 0; k < 4; ++k) {
                    aL[k] += blo(uu[c][k]);
                    aH[k] += bhi(uu[c][k]);
                }
            }
        }
    }

    // fold subgroup partials, add self-loop
#pragma unroll
    for (int k = 0; k < 4; ++k) {
        aL[k] += __shfl_xor(aL[k], 16); aL[k] += __shfl_xor(aL[k], 32);
        aH[k] += __shfl_xor(aH[k], 16); aH[k] += __shfl_xor(aH[k], 32);
        aL[k] += blo(u0[k]);
        aH[k] += bhi(u0[k]);
    }

    const float dd = dinv[d];
    float vL[4], vH[4];
    float s = 0.f, s2 = 0.f;
#pragma unroll
    for (int k = 0; k < 4; ++k) {
        int c = colL + k;
        vL[k] = aL[k] * dd + b[c];
        vH[k] = aH[k] * dd + b[c + 16];
        s  += vL[k] + vH[k];
        s2 += vL[k] * vL[k] + vH[k] * vH[k];
    }
#pragma unroll
    for (int off = 1; off < 16; off <<= 1) {
        s  += __shfl_xor(s,  off);
        s2 += __shfl_xor(s2, off);
    }
    float mu   = s  * (1.0f / 128.0f);
    float var  = s2 * (1.0f / 128.0f) - mu * mu;
    float rstd = rsqrtf(var + 1e-5f);

    // each subgroup finishes 2 of the 8 replicated values: k = sg
    int c0 = colL + sg, c1 = colL + 16 + sg;
    float o0 = gelu_exact((vL[sg] - mu) * rstd * g[c0] + be[c0]);
    float o1 = gelu_exact((vH[sg] - mu) * rstd * g[c1] + be[c1]);

    if (OUT_F32) {
        outf[(size_t)d * HID + c0] = o0;
        outf[(size_t)d * HID + c1] = o1;
    } else {
        z1[(size_t)d * HID + c0] = f2b(o0);
        z1[(size_t)d * HID + c1] = f2b(o1);
    }
}

// ---------------------------------------------------------------- launch ----
extern "C" void kernel_launch(void* const* d_in, const int* in_sizes, int n_in,
                              void* d_out, int out_size, void* d_ws, size_t ws_size,
                              hipStream_t stream) {
    const float* x   = (const float*)d_in[0];
    const int*   ei  = (const int*)d_in[1];   // [2, E] int32
    const float* W1  = (const float*)d_in[2];
    const float* b1  = (const float*)d_in[3];
    const float* W2  = (const float*)d_in[4];
    const float* b2  = (const float*)d_in[5];
    const float* g1  = (const float*)d_in[6];
    const float* be1 = (const float*)d_in[7];
    const float* g2  = (const float*)d_in[8];
    const float* be2 = (const float*)d_in[9];
    float* out = (float*)d_out;

    const int* src = ei;
    const int* dst = ei + N_EDGES;

    // ws: hs packed [N+1][64] u32 | z1 bf16 [N][128] | srcPerm [E]
    //     | dinv [N] | offs [N] | cnt [N+pad] | bsum [256] | wfrag [2][8192]
    uint*   hs      = (uint*)d_ws;
    ushort* z1      = (ushort*)(hs + (size_t)(N_NODES + 1) * 64);
    int*    srcPerm = (int*)(z1 + (size_t)N_NODES * HID);
    float*  dinv    = (float*)(srcPerm + N_EDGES);
    int*    offs    = (int*)(dinv + N_NODES);
    int*    cnt     = offs + N_NODES;
    int*    bsum    = cnt + 50016;               // cnt padded to /16
    uint*   wfrag   = (uint*)(bsum + 256);

    const int B = 256;
    const int nodeB = (N_NODES + B - 1) / B;            // 196
    const int e4    = N_EDGES / 4;                      // 150000 (exact)
    const int edge4B = (e4 + B - 1) / B;                // 586
    const int gemm_blocks = (N_NODES + 63) / 64;        // 782
    const int agg_blocks  = N_NODES / 4;                // 12500 (exact)
    const int zero4 = 50016 / 4;                        // 12504
    const int prepB = (16384 + zero4 + 16 + B - 1) / B; // 113

    // prep (wfrag + cnt zero + hs zero-row), degree, dinv, scan, fill
    prep_kernel<<<prepB, B, 0, stream>>>(W1, W2, wfrag, (u32x4*)cnt, zero4,
                                         (u32x4*)hs);
    count_deg_kernel<<<edge4B, B, 0, stream>>>((const int4*)dst, cnt, e4);
    reduce_dinv_kernel<<<nodeB, B, 0, stream>>>(cnt, dinv, bsum, N_NODES);
    scan_csr_kernel<<<nodeB, B, 0, stream>>>(cnt, bsum, offs, N_NODES, nodeB);
    fill_csr_kernel<<<edge4B, B, 0, stream>>>((const int4*)src, (const int4*)dst,
                                              offs, srcPerm, e4);
    // post-fill: offs[d] == end of segment d

    // ---- layer 1 ----
    gemm1_kernel<<<gemm_blocks, B, 0, stream>>>(x, wfrag, dinv, hs);
    agg_ln_kernel<false><<<agg_blocks, B, 0, stream>>>(
        (const u32x4*)hs, dinv, offs, srcPerm, b1, g1, be1, z1, nullptr);

    // ---- layer 2 ----
    gemm2_kernel<<<gemm_blocks, B, 0, stream>>>(z1, wfrag + 8192, dinv, hs);
    agg_ln_kernel<true><<<agg_blocks, B, 0, stream>>>(
        (const u32x4*)hs, dinv, offs, srcPerm, b2, g2, be2, nullptr, out);
}